// Round 12
// baseline (163.699 us; speedup 1.0000x reference)
//
#include <hip/hip_runtime.h>
#include <math.h>

#define NNODES 20000
#define NEDGES 320000
#define MPAD   20096          // 628 * 32
#define MAXDEG 64

typedef __attribute__((ext_vector_type(8))) short bf16x8;
typedef __attribute__((ext_vector_type(4))) float f32x4;

__device__ __forceinline__ short f2bf(float f) {
    unsigned u = __builtin_bit_cast(unsigned, f);
    u += 0x7fff + ((u >> 16) & 1);
    return (short)(u >> 16);
}
__device__ __forceinline__ float bf2f(unsigned short u) {
    return __builtin_bit_cast(float, (unsigned)u << 16);
}
__device__ __forceinline__ void gload16(const void* g, void* l) {
    __builtin_amdgcn_global_load_lds((const __attribute__((address_space(1))) void*)g,
                                     (__attribute__((address_space(3))) void*)l, 16, 0, 0);
}

// ================================================================ fused prep
// Weights -> FRAGMENT-MAJOR bf16: W*F[((T*KC+C)*64+L)*8+j] = W[k][n],
//   n = T*16+(L&15), k = C*32+(L>>4)*8+j
__global__ __launch_bounds__(256) void k_prep(const float* __restrict__ c0W1,
                                              const float* __restrict__ csW1,
                                              const float* __restrict__ c0W2,
                                              const float* __restrict__ csW2,
                                              const float* __restrict__ x,
                                              const float* __restrict__ ni,
                                              short* __restrict__ wT,
                                              short* __restrict__ xb,
                                              int* __restrict__ cnt) {
    int i = blockIdx.x * 256 + threadIdx.x;
    if (i < 720896) {
        const float* src; int N2, base, kcLog;
        if (i < 65536)       { src = c0W1;          base = 0;      N2 = 512; kcLog = 2; }
        else if (i < 196608) { src = csW1;          base = 65536;  N2 = 512; kcLog = 3; }
        else if (i < 327680) { src = csW1 + 131072; base = 196608; N2 = 512; kcLog = 3; }
        else if (i < 458752) { src = c0W2;          base = 327680; N2 = 256; kcLog = 4; }
        else if (i < 589824) { src = csW2;          base = 458752; N2 = 256; kcLog = 4; }
        else                 { src = csW2 + 131072; base = 589824; N2 = 256; kcLog = 4; }
        int jj = i - base;
        int j = jj & 7;
        int L = (jj >> 3) & 63;
        int rest = jj >> 9;
        int C = rest & ((1 << kcLog) - 1);
        int T = rest >> kcLog;
        int n = T * 16 + (L & 15);
        int k = C * 32 + ((L >> 4) << 3) + j;
        wT[i] = f2bf(src[(size_t)k * N2 + n]);
        return;
    }
    int j = i - 720896;
    if (j < NNODES * 16) {
        float s = ni[j >> 4];
        float4 a = reinterpret_cast<const float4*>(x)[j * 2];
        float4 b = reinterpret_cast<const float4*>(x)[j * 2 + 1];
        ushort e[8];
        e[0] = (ushort)f2bf(a.x * s); e[1] = (ushort)f2bf(a.y * s);
        e[2] = (ushort)f2bf(a.z * s); e[3] = (ushort)f2bf(a.w * s);
        e[4] = (ushort)f2bf(b.x * s); e[5] = (ushort)f2bf(b.y * s);
        e[6] = (ushort)f2bf(b.z * s); e[7] = (ushort)f2bf(b.w * s);
        uint4 o;
        o.x = e[0] | ((unsigned)e[1] << 16);
        o.y = e[2] | ((unsigned)e[3] << 16);
        o.z = e[4] | ((unsigned)e[5] << 16);
        o.w = e[6] | ((unsigned)e[7] << 16);
        reinterpret_cast<uint4*>(xb)[j] = o;
        return;
    }
    int k = j - NNODES * 16;
    if (k < NNODES) cnt[k] = 0;
}

// ================================================================ bucket fill
__global__ __launch_bounds__(256) void k_fill(const int* __restrict__ dst,
                                              const int* __restrict__ src,
                                              const float* __restrict__ ew,
                                              int* __restrict__ cnt,
                                              int2* __restrict__ edgb) {
    int e = blockIdx.x * 256 + threadIdx.x;
    if (e >= NEDGES) return;
    int d = dst[e];
    int slot = atomicAdd(&cnt[d], 1);
    if (slot < MAXDEG)
        edgb[(size_t)d * MAXDEG + slot] = make_int2(src[e], __builtin_bit_cast(int, ew[e]));
}

// ================================================================ gather layer 0
__global__ __launch_bounds__(256) void k_agg0(const int2* __restrict__ edgb,
                                              const int* __restrict__ cnt,
                                              const short* __restrict__ xb,
                                              const float* __restrict__ epsp,
                                              short* __restrict__ z) {
    int node = (blockIdx.x * 256 + threadIdx.x) >> 5;
    int lane = threadIdx.x & 31;
    if (node >= NNODES) return;
    const float eps1 = 1.0f + epsp[0];
    const int4* eb4 = reinterpret_cast<const int4*>(edgb + (size_t)node * MAXDEG);
    int p1 = min(cnt[node], MAXDEG);
    uint2 hv = *reinterpret_cast<const uint2*>(xb + (size_t)node * 128 + lane * 4);
    float a0 = eps1 * __builtin_bit_cast(float, hv.x << 16);
    float a1 = eps1 * __builtin_bit_cast(float, hv.x & 0xffff0000u);
    float a2 = eps1 * __builtin_bit_cast(float, hv.y << 16);
    float a3 = eps1 * __builtin_bit_cast(float, hv.y & 0xffff0000u);
    float b0 = 0.f, b1 = 0.f, b2 = 0.f, b3 = 0.f;
    int p = 0;
    for (; p + 3 < p1; p += 4) {
        int4 e01 = eb4[p >> 1], e23 = eb4[(p >> 1) + 1];
        float w0 = __builtin_bit_cast(float, e01.y);
        float w1 = __builtin_bit_cast(float, e01.w);
        float w2 = __builtin_bit_cast(float, e23.y);
        float w3 = __builtin_bit_cast(float, e23.w);
        uint2 v0 = *reinterpret_cast<const uint2*>(xb + (size_t)e01.x * 128 + lane * 4);
        uint2 v1 = *reinterpret_cast<const uint2*>(xb + (size_t)e01.z * 128 + lane * 4);
        uint2 v2 = *reinterpret_cast<const uint2*>(xb + (size_t)e23.x * 128 + lane * 4);
        uint2 v3 = *reinterpret_cast<const uint2*>(xb + (size_t)e23.z * 128 + lane * 4);
        a0 += fmaxf(__builtin_bit_cast(float, v0.x << 16) * w0, 0.f);
        a1 += fmaxf(__builtin_bit_cast(float, v0.x & 0xffff0000u) * w0, 0.f);
        a2 += fmaxf(__builtin_bit_cast(float, v0.y << 16) * w0, 0.f);
        a3 += fmaxf(__builtin_bit_cast(float, v0.y & 0xffff0000u) * w0, 0.f);
        b0 += fmaxf(__builtin_bit_cast(float, v1.x << 16) * w1, 0.f);
        b1 += fmaxf(__builtin_bit_cast(float, v1.x & 0xffff0000u) * w1, 0.f);
        b2 += fmaxf(__builtin_bit_cast(float, v1.y << 16) * w1, 0.f);
        b3 += fmaxf(__builtin_bit_cast(float, v1.y & 0xffff0000u) * w1, 0.f);
        a0 += fmaxf(__builtin_bit_cast(float, v2.x << 16) * w2, 0.f);
        a1 += fmaxf(__builtin_bit_cast(float, v2.x & 0xffff0000u) * w2, 0.f);
        a2 += fmaxf(__builtin_bit_cast(float, v2.y << 16) * w2, 0.f);
        a3 += fmaxf(__builtin_bit_cast(float, v2.y & 0xffff0000u) * w2, 0.f);
        b0 += fmaxf(__builtin_bit_cast(float, v3.x << 16) * w3, 0.f);
        b1 += fmaxf(__builtin_bit_cast(float, v3.x & 0xffff0000u) * w3, 0.f);
        b2 += fmaxf(__builtin_bit_cast(float, v3.y << 16) * w3, 0.f);
        b3 += fmaxf(__builtin_bit_cast(float, v3.y & 0xffff0000u) * w3, 0.f);
    }
    const int2* eb = reinterpret_cast<const int2*>(eb4);
    for (; p < p1; ++p) {
        int2 q0 = eb[p];
        float w0 = __builtin_bit_cast(float, q0.y);
        uint2 v0 = *reinterpret_cast<const uint2*>(xb + (size_t)q0.x * 128 + lane * 4);
        a0 += fmaxf(__builtin_bit_cast(float, v0.x << 16) * w0, 0.f);
        a1 += fmaxf(__builtin_bit_cast(float, v0.x & 0xffff0000u) * w0, 0.f);
        a2 += fmaxf(__builtin_bit_cast(float, v0.y << 16) * w0, 0.f);
        a3 += fmaxf(__builtin_bit_cast(float, v0.y & 0xffff0000u) * w0, 0.f);
    }
    short4 o;
    o.x = f2bf(a0 + b0); o.y = f2bf(a1 + b1); o.z = f2bf(a2 + b2); o.w = f2bf(a3 + b3);
    *reinterpret_cast<short4*>(z + (size_t)node * 128 + lane * 4) = o;
}

// ================================================================ gather layers 1,2 (wave/node, scalar meta)
__global__ __launch_bounds__(256) void k_agg256(const int2* __restrict__ edgb,
                                                const int* __restrict__ cnt,
                                                const short* __restrict__ h,
                                                const float* __restrict__ epsp,
                                                short* __restrict__ z) {
    int node = (blockIdx.x * 256 + threadIdx.x) >> 6;
    int lane = threadIdx.x & 63;
    if (node >= NNODES) return;
    node = __builtin_amdgcn_readfirstlane(node);
    const float eps1 = 1.0f + epsp[0];
    const int2* eb = edgb + (size_t)node * MAXDEG;
    int p1 = min(cnt[node], MAXDEG);
    uint2 hv = *reinterpret_cast<const uint2*>(h + (size_t)node * 256 + lane * 4);
    float a0 = eps1 * __builtin_bit_cast(float, hv.x << 16);
    float a1 = eps1 * __builtin_bit_cast(float, hv.x & 0xffff0000u);
    float a2 = eps1 * __builtin_bit_cast(float, hv.y << 16);
    float a3 = eps1 * __builtin_bit_cast(float, hv.y & 0xffff0000u);
    float b0 = 0.f, b1 = 0.f, b2 = 0.f, b3 = 0.f;
    int p = 0;
    for (; p + 3 < p1; p += 4) {
        int2 q0 = eb[p], q1 = eb[p + 1], q2 = eb[p + 2], q3 = eb[p + 3];
        float w0 = __builtin_bit_cast(float, q0.y);
        float w1 = __builtin_bit_cast(float, q1.y);
        float w2 = __builtin_bit_cast(float, q2.y);
        float w3 = __builtin_bit_cast(float, q3.y);
        uint2 v0 = *reinterpret_cast<const uint2*>(h + (size_t)q0.x * 256 + lane * 4);
        uint2 v1 = *reinterpret_cast<const uint2*>(h + (size_t)q1.x * 256 + lane * 4);
        uint2 v2 = *reinterpret_cast<const uint2*>(h + (size_t)q2.x * 256 + lane * 4);
        uint2 v3 = *reinterpret_cast<const uint2*>(h + (size_t)q3.x * 256 + lane * 4);
        a0 += __builtin_bit_cast(float, v0.x << 16) * w0;
        a1 += __builtin_bit_cast(float, v0.x & 0xffff0000u) * w0;
        a2 += __builtin_bit_cast(float, v0.y << 16) * w0;
        a3 += __builtin_bit_cast(float, v0.y & 0xffff0000u) * w0;
        b0 += __builtin_bit_cast(float, v1.x << 16) * w1;
        b1 += __builtin_bit_cast(float, v1.x & 0xffff0000u) * w1;
        b2 += __builtin_bit_cast(float, v1.y << 16) * w1;
        b3 += __builtin_bit_cast(float, v1.y & 0xffff0000u) * w1;
        a0 += __builtin_bit_cast(float, v2.x << 16) * w2;
        a1 += __builtin_bit_cast(float, v2.x & 0xffff0000u) * w2;
        a2 += __builtin_bit_cast(float, v2.y << 16) * w2;
        a3 += __builtin_bit_cast(float, v2.y & 0xffff0000u) * w2;
        b0 += __builtin_bit_cast(float, v3.x << 16) * w3;
        b1 += __builtin_bit_cast(float, v3.x & 0xffff0000u) * w3;
        b2 += __builtin_bit_cast(float, v3.y << 16) * w3;
        b3 += __builtin_bit_cast(float, v3.y & 0xffff0000u) * w3;
    }
    for (; p < p1; ++p) {
        int2 q0 = eb[p];
        float w0 = __builtin_bit_cast(float, q0.y);
        uint2 v0 = *reinterpret_cast<const uint2*>(h + (size_t)q0.x * 256 + lane * 4);
        a0 += __builtin_bit_cast(float, v0.x << 16) * w0;
        a1 += __builtin_bit_cast(float, v0.x & 0xffff0000u) * w0;
        a2 += __builtin_bit_cast(float, v0.y << 16) * w0;
        a3 += __builtin_bit_cast(float, v0.y & 0xffff0000u) * w0;
    }
    ushort e0 = (ushort)f2bf(a0 + b0), e1 = (ushort)f2bf(a1 + b1);
    ushort e2 = (ushort)f2bf(a2 + b2), e3 = (ushort)f2bf(a3 + b3);
    uint2 ov;
    ov.x = e0 | ((unsigned)e1 << 16);
    ov.y = e2 | ((unsigned)e3 << 16);
    *reinterpret_cast<uint2*>(z + (size_t)node * 256 + lane * 4) = ov;
}

// ================================================================ fused MLP, 32-row blocks, 4 blocks/CU
// 628 blocks x 512 thr; LDS 32KB (zs 16 + tbuf 16) -> 4 blocks/CU = 32 waves (full occ).
// Each wave: all 32 rows (m=2), 32-col slice (n=2). Weight frag feeds 2 MFMAs.
template<int DIN, bool RELU_OUT, bool FUSE_ATT>
__global__ __launch_bounds__(512, 4) void k_mlp(
    const short* __restrict__ zin,   // [MPAD][DIN]
    const short* __restrict__ W1F,   // fragment-major, T=32, KC=DIN/32
    const float* __restrict__ b1, const float* __restrict__ bn1,  // [4][512]
    const short* __restrict__ W2F,   // fragment-major, T=16, KC=16
    const float* __restrict__ b2, const float* __restrict__ bn2,  // [4][256]
    short* __restrict__ hout,        // [MPAD][256]
    const float* __restrict__ attW, const float* __restrict__ attb,
    float* __restrict__ nkout)
{
    __shared__ __align__(16) short zs[32 * DIN];     // 16 KB (8 KB layer0)
    __shared__ __align__(16) short tbuf[32 * 256];   // 16 KB

    const int tid = threadIdx.x;
    const int r0 = blockIdx.x * 32;
    const int lane = tid & 63;
    const int wc = tid >> 6;          // wave 0..7 -> 32-col slice
    constexpr int KC1 = DIN / 32;
    constexpr int CH = DIN / 8;       // 16B chunks per row

    // stage z[32][DIN]
    #pragma unroll
    for (int i = 0; i < 32 * CH / 512; ++i) {
        int cid = i * 512 + tid;
        int r = cid / CH, cl = cid & (CH - 1);
        gload16(zin + (size_t)(r0 + r) * DIN + ((cl ^ (r & 7)) << 3),
                (char*)zs + cid * 16);
    }
    __syncthreads();

    f32x4 acc2[2][2];
    #pragma unroll
    for (int m = 0; m < 2; ++m)
        #pragma unroll
        for (int n = 0; n < 2; ++n)
            acc2[m][n] = (f32x4){0.f, 0.f, 0.f, 0.f};

    #pragma unroll
    for (int g = 0; g < 2; ++g) {
        // ---- phase 1: t[:, g*256:(g+1)*256] -> tbuf
        f32x4 acc[2][2];
        #pragma unroll
        for (int m = 0; m < 2; ++m)
            #pragma unroll
            for (int n = 0; n < 2; ++n)
                acc[m][n] = (f32x4){0.f, 0.f, 0.f, 0.f};
        #pragma unroll
        for (int kt = 0; kt < DIN; kt += 64) {
            #pragma unroll
            for (int ks = 0; ks < 2; ++ks) {
                bf16x8 af[2], bfr[2];
                #pragma unroll
                for (int m = 0; m < 2; ++m) {
                    int zr = m * 16 + (lane & 15);
                    int zc = (kt >> 3) + ks * 4 + (lane >> 4);
                    af[m] = *(const bf16x8*)((const char*)zs + zr * (DIN * 2)
                                             + ((zc ^ (zr & 7)) << 4));
                }
                #pragma unroll
                for (int n = 0; n < 2; ++n) {
                    int T = g * 16 + wc * 2 + n;
                    int C = (kt >> 5) + ks;
                    bfr[n] = *(const bf16x8*)(W1F + (((size_t)T * KC1 + C) * 64 + lane) * 8);
                }
                #pragma unroll
                for (int m = 0; m < 2; ++m)
                    #pragma unroll
                    for (int n = 0; n < 2; ++n)
                        acc[m][n] = __builtin_amdgcn_mfma_f32_16x16x32_bf16(bfr[n], af[m], acc[m][n], 0, 0, 0);
            }
        }
        {
            const int cb = wc * 32 + 4 * (lane >> 4);
            #pragma unroll
            for (int n = 0; n < 2; ++n) {
                int c = cb + n * 16;
                int gc = g * 256 + c;
                float4 ga = *reinterpret_cast<const float4*>(bn1 + gc);
                float4 be = *reinterpret_cast<const float4*>(bn1 + 512 + gc);
                float4 mu = *reinterpret_cast<const float4*>(bn1 + 1024 + gc);
                float4 va = *reinterpret_cast<const float4*>(bn1 + 1536 + gc);
                float4 bi = *reinterpret_cast<const float4*>(b1 + gc);
                float sx = ga.x * rsqrtf(va.x + 1e-5f);
                float sy = ga.y * rsqrtf(va.y + 1e-5f);
                float sz = ga.z * rsqrtf(va.z + 1e-5f);
                float sw = ga.w * rsqrtf(va.w + 1e-5f);
                float hx = be.x - mu.x * sx + bi.x * sx;
                float hy = be.y - mu.y * sy + bi.y * sy;
                float hz = be.z - mu.z * sz + bi.z * sz;
                float hw_ = be.w - mu.w * sw + bi.w * sw;
                #pragma unroll
                for (int m = 0; m < 2; ++m) {
                    int r = m * 16 + (lane & 15);
                    float o0 = fmaxf(acc[m][n][0] * sx + hx, 0.f);
                    float o1 = fmaxf(acc[m][n][1] * sy + hy, 0.f);
                    float o2 = fmaxf(acc[m][n][2] * sz + hz, 0.f);
                    float o3 = fmaxf(acc[m][n][3] * sw + hw_, 0.f);
                    ushort e0 = (ushort)f2bf(o0), e1 = (ushort)f2bf(o1);
                    ushort e2 = (ushort)f2bf(o2), e3 = (ushort)f2bf(o3);
                    uint2 ov;
                    ov.x = e0 | ((unsigned)e1 << 16);
                    ov.y = e2 | ((unsigned)e3 << 16);
                    *reinterpret_cast<uint2*>((char*)tbuf + r * 512
                                              + (((c >> 3) ^ (r & 7)) << 4) + ((c & 4) << 1)) = ov;
                }
            }
        }
        __syncthreads();

        // ---- phase 2 partial: acc2 += t_group @ W2[g*256:(g+1)*256, :]
        #pragma unroll
        for (int kt = 0; kt < 256; kt += 64) {
            #pragma unroll
            for (int ks = 0; ks < 2; ++ks) {
                bf16x8 af[2], bfr[2];
                #pragma unroll
                for (int m = 0; m < 2; ++m) {
                    int tr = m * 16 + (lane & 15);
                    int tc = (kt >> 3) + ks * 4 + (lane >> 4);
                    af[m] = *(const bf16x8*)((const char*)tbuf + tr * 512
                                             + ((tc ^ (tr & 7)) << 4));
                }
                #pragma unroll
                for (int n = 0; n < 2; ++n) {
                    int T2 = wc * 2 + n;
                    int C2 = g * 8 + (kt >> 5) + ks;
                    bfr[n] = *(const bf16x8*)(W2F + (((size_t)T2 * 16 + C2) * 64 + lane) * 8);
                }
                #pragma unroll
                for (int m = 0; m < 2; ++m)
                    #pragma unroll
                    for (int n = 0; n < 2; ++n)
                        acc2[m][n] = __builtin_amdgcn_mfma_f32_16x16x32_bf16(bfr[n], af[m], acc2[m][n], 0, 0, 0);
            }
        }
        if (g == 0) __syncthreads();
    }

    // ---- final epilogue
    {
        const int cb = wc * 32 + 4 * (lane >> 4);
        float4 scl[2], shf[2];
        #pragma unroll
        for (int n = 0; n < 2; ++n) {
            int c = cb + n * 16;
            float4 ga = *reinterpret_cast<const float4*>(bn2 + c);
            float4 be = *reinterpret_cast<const float4*>(bn2 + 256 + c);
            float4 mu = *reinterpret_cast<const float4*>(bn2 + 512 + c);
            float4 va = *reinterpret_cast<const float4*>(bn2 + 768 + c);
            float4 bi = *reinterpret_cast<const float4*>(b2 + c);
            scl[n].x = ga.x * rsqrtf(va.x + 1e-5f);
            scl[n].y = ga.y * rsqrtf(va.y + 1e-5f);
            scl[n].z = ga.z * rsqrtf(va.z + 1e-5f);
            scl[n].w = ga.w * rsqrtf(va.w + 1e-5f);
            shf[n].x = be.x - mu.x * scl[n].x + bi.x * scl[n].x;
            shf[n].y = be.y - mu.y * scl[n].y + bi.y * scl[n].y;
            shf[n].z = be.z - mu.z * scl[n].z + bi.z * scl[n].z;
            shf[n].w = be.w - mu.w * scl[n].w + bi.w * scl[n].w;
        }
        if constexpr (!FUSE_ATT) {
            #pragma unroll
            for (int n = 0; n < 2; ++n) {
                int c = cb + n * 16;
                #pragma unroll
                for (int m = 0; m < 2; ++m) {
                    int r = r0 + m * 16 + (lane & 15);
                    float o0 = acc2[m][n][0] * scl[n].x + shf[n].x;
                    float o1 = acc2[m][n][1] * scl[n].y + shf[n].y;
                    float o2 = acc2[m][n][2] * scl[n].z + shf[n].z;
                    float o3 = acc2[m][n][3] * scl[n].w + shf[n].w;
                    if (RELU_OUT) {
                        o0 = fmaxf(o0, 0.f); o1 = fmaxf(o1, 0.f);
                        o2 = fmaxf(o2, 0.f); o3 = fmaxf(o3, 0.f);
                    }
                    short4 ov;
                    ov.x = f2bf(o0); ov.y = f2bf(o1); ov.z = f2bf(o2); ov.w = f2bf(o3);
                    *reinterpret_cast<short4*>(hout + (size_t)r * 256 + c) = ov;
                }
            }
        } else {
            float* attp = (float*)zs;
            #pragma unroll
            for (int m = 0; m < 2; ++m) {
                float s = 0.f;
                #pragma unroll
                for (int n = 0; n < 2; ++n) {
                    int c = cb + n * 16;
                    float4 aw = *reinterpret_cast<const float4*>(attW + c);
                    float o0 = acc2[m][n][0] * scl[n].x + shf[n].x;
                    float o1 = acc2[m][n][1] * scl[n].y + shf[n].y;
                    float o2 = acc2[m][n][2] * scl[n].z + shf[n].z;
                    float o3 = acc2[m][n][3] * scl[n].w + shf[n].w;
                    s += bf2f((ushort)f2bf(o0)) * aw.x + bf2f((ushort)f2bf(o1)) * aw.y
                       + bf2f((ushort)f2bf(o2)) * aw.z + bf2f((ushort)f2bf(o3)) * aw.w;
                }
                s += __shfl_xor(s, 16);
                s += __shfl_xor(s, 32);
                if (lane < 16) attp[wc * 32 + m * 16 + lane] = s;
            }
            __syncthreads();
            if (tid < 32) {
                float d = 0.f;
                #pragma unroll
                for (int w2 = 0; w2 < 8; ++w2) d += attp[w2 * 32 + tid];
                int r = r0 + tid;
                if (r < NNODES)
                    nkout[r] = 1.f / (1.f + expf(-(d + attb[0])));
            }
        }
    }
}

// ================================================================ edge keys
__global__ __launch_bounds__(256) void k_edge(const int* __restrict__ ei,
                                              const float* __restrict__ nk,
                                              float* __restrict__ ek) {
    int e = blockIdx.x * 256 + threadIdx.x;
    if (e >= NEDGES) return;
    ek[e] = nk[ei[e]] * nk[ei[NEDGES + e]];
}

// ================================================================
extern "C" void kernel_launch(void* const* d_in, const int* in_sizes, int n_in,
                              void* d_out, int out_size, void* d_ws, size_t ws_size,
                              hipStream_t stream) {
    const float* x        = (const float*)d_in[0];
    const int*   ei       = (const int*)d_in[1];
    const float* node_imp = (const float*)d_in[2];
    const float* edge_imp = (const float*)d_in[3];
    const float* c0_W1    = (const float*)d_in[4];
    const float* c0_b1    = (const float*)d_in[5];
    const float* c0_bn    = (const float*)d_in[6];
    const float* c0_W2    = (const float*)d_in[7];
    const float* c0_b2    = (const float*)d_in[8];
    const float* c0_eps   = (const float*)d_in[9];
    const float* cs_W1    = (const float*)d_in[10];
    const float* cs_b1    = (const float*)d_in[11];
    const float* cs_bn    = (const float*)d_in[12];
    const float* cs_W2    = (const float*)d_in[13];
    const float* cs_b2    = (const float*)d_in[14];
    const float* cs_eps   = (const float*)d_in[15];
    const float* obn      = (const float*)d_in[16];
    const float* att_W    = (const float*)d_in[17];
    const float* att_b    = (const float*)d_in[18];
    float* out = (float*)d_out;

    const int* e_src = ei;
    const int* e_dst = ei + NEDGES;

    // workspace layout
    short* hA  = (short*)d_ws;                  // [MPAD][256]
    short* hBv = hA + (size_t)MPAD * 256;       // [MPAD][256]
    short* zb  = hBv + (size_t)MPAD * 256;      // [MPAD][256]
    short* wT  = zb + (size_t)MPAD * 256;       // 720896 bf16 (fragment-major)
    short* xb  = wT + 720896;                   // [MPAD][128]
    int2*  edgb = (int2*)(xb + (size_t)MPAD * 128);        // [NNODES][MAXDEG]
    int*   cnt  = (int*)(edgb + (size_t)NNODES * MAXDEG);  // N

    const short* WT_c0W1  = wT + 0;
    const short* WT_cs1_0 = wT + 65536;
    const short* WT_cs1_1 = wT + 196608;
    const short* WT_c0W2  = wT + 327680;
    const short* WT_cs2_0 = wT + 458752;
    const short* WT_cs2_1 = wT + 589824;

    dim3 blk(256);
    const int eb = (NEDGES + 255) / 256;
    const int mgrid = MPAD / 32;   // 628
    const int agrid0 = (NNODES * 32 + 255) / 256;
    const int agrid1 = (NNODES * 64 + 255) / 256;

    // ---- prep (weights + xb + cnt zero) + bucket fill
    const int prepN = 720896 + NNODES * 16 + NNODES;
    k_prep<<<(prepN + 255) / 256, blk, 0, stream>>>(c0_W1, cs_W1, c0_W2, cs_W2,
                                                    x, node_imp, wT, xb, cnt);
    k_fill<<<eb, blk, 0, stream>>>(e_dst, e_src, edge_imp, cnt, edgb);

    // ---- layer 0
    k_agg0<<<agrid0, blk, 0, stream>>>(edgb, cnt, xb, c0_eps, zb);
    k_mlp<128, true, false><<<mgrid, 512, 0, stream>>>(zb, WT_c0W1, c0_b1, c0_bn,
        WT_c0W2, c0_b2, obn, hA, nullptr, nullptr, nullptr);
    // ---- layer 1
    k_agg256<<<agrid1, blk, 0, stream>>>(edgb, cnt, hA, cs_eps, zb);
    k_mlp<256, true, false><<<mgrid, 512, 0, stream>>>(zb, WT_cs1_0, cs_b1, cs_bn,
        WT_cs2_0, cs_b2, obn + 1024, hBv, nullptr, nullptr, nullptr);
    // ---- layer 2 (+ fused attention -> nk in d_out)
    k_agg256<<<agrid1, blk, 0, stream>>>(edgb, cnt, hBv, cs_eps + 1, zb);
    k_mlp<256, false, true><<<mgrid, 512, 0, stream>>>(zb, WT_cs1_1, cs_b1 + 512, cs_bn + 2048,
        WT_cs2_1, cs_b2 + 256, obn + 2048, nullptr, att_W, att_b, out);

    // ---- edge keys
    k_edge<<<eb, blk, 0, stream>>>(ei, out, out + NNODES);
}

// Round 13
// 153.750 us; speedup vs baseline: 1.0647x; 1.0647x over previous
//
#include <hip/hip_runtime.h>
#include <math.h>

#define NNODES 20000
#define NEDGES 320000
#define MPAD   20096          // 314 * 64
#define MAXDEG 64

typedef __attribute__((ext_vector_type(8))) short bf16x8;
typedef __attribute__((ext_vector_type(4))) float f32x4;

__device__ __forceinline__ short f2bf(float f) {
    unsigned u = __builtin_bit_cast(unsigned, f);
    u += 0x7fff + ((u >> 16) & 1);
    return (short)(u >> 16);
}
__device__ __forceinline__ float bf2f(unsigned short u) {
    return __builtin_bit_cast(float, (unsigned)u << 16);
}
__device__ __forceinline__ void gload16(const void* g, void* l) {
    __builtin_amdgcn_global_load_lds((const __attribute__((address_space(1))) void*)g,
                                     (__attribute__((address_space(3))) void*)l, 16, 0, 0);
}

// ================================================================ fused prep
// Weights -> FRAGMENT-MAJOR bf16: W*F[((T*KC+C)*64+L)*8+j] = W[k][n],
//   n = T*16+(L&15), k = C*32+(L>>4)*8+j
__global__ __launch_bounds__(256) void k_prep(const float* __restrict__ c0W1,
                                              const float* __restrict__ csW1,
                                              const float* __restrict__ c0W2,
                                              const float* __restrict__ csW2,
                                              const float* __restrict__ x,
                                              const float* __restrict__ ni,
                                              short* __restrict__ wT,
                                              short* __restrict__ xb,
                                              int* __restrict__ cnt) {
    int i = blockIdx.x * 256 + threadIdx.x;
    if (i < 720896) {
        const float* src; int N2, base, kcLog;
        if (i < 65536)       { src = c0W1;          base = 0;      N2 = 512; kcLog = 2; }
        else if (i < 196608) { src = csW1;          base = 65536;  N2 = 512; kcLog = 3; }
        else if (i < 327680) { src = csW1 + 131072; base = 196608; N2 = 512; kcLog = 3; }
        else if (i < 458752) { src = c0W2;          base = 327680; N2 = 256; kcLog = 4; }
        else if (i < 589824) { src = csW2;          base = 458752; N2 = 256; kcLog = 4; }
        else                 { src = csW2 + 131072; base = 589824; N2 = 256; kcLog = 4; }
        int jj = i - base;
        int j = jj & 7;
        int L = (jj >> 3) & 63;
        int rest = jj >> 9;
        int C = rest & ((1 << kcLog) - 1);
        int T = rest >> kcLog;
        int n = T * 16 + (L & 15);
        int k = C * 32 + ((L >> 4) << 3) + j;
        wT[i] = f2bf(src[(size_t)k * N2 + n]);
        return;
    }
    int j = i - 720896;
    if (j < NNODES * 16) {
        float s = ni[j >> 4];
        float4 a = reinterpret_cast<const float4*>(x)[j * 2];
        float4 b = reinterpret_cast<const float4*>(x)[j * 2 + 1];
        ushort e[8];
        e[0] = (ushort)f2bf(a.x * s); e[1] = (ushort)f2bf(a.y * s);
        e[2] = (ushort)f2bf(a.z * s); e[3] = (ushort)f2bf(a.w * s);
        e[4] = (ushort)f2bf(b.x * s); e[5] = (ushort)f2bf(b.y * s);
        e[6] = (ushort)f2bf(b.z * s); e[7] = (ushort)f2bf(b.w * s);
        uint4 o;
        o.x = e[0] | ((unsigned)e[1] << 16);
        o.y = e[2] | ((unsigned)e[3] << 16);
        o.z = e[4] | ((unsigned)e[5] << 16);
        o.w = e[6] | ((unsigned)e[7] << 16);
        reinterpret_cast<uint4*>(xb)[j] = o;
        return;
    }
    int k = j - NNODES * 16;
    if (k < NNODES) cnt[k] = 0;
}

// ================================================================ bucket fill
__global__ __launch_bounds__(256) void k_fill(const int* __restrict__ dst,
                                              const int* __restrict__ src,
                                              const float* __restrict__ ew,
                                              int* __restrict__ cnt,
                                              int2* __restrict__ edgb) {
    int e = blockIdx.x * 256 + threadIdx.x;
    if (e >= NEDGES) return;
    int d = dst[e];
    int slot = atomicAdd(&cnt[d], 1);
    if (slot < MAXDEG)
        edgb[(size_t)d * MAXDEG + slot] = make_int2(src[e], __builtin_bit_cast(int, ew[e]));
}

// ================================================================ gather layer 0
__global__ __launch_bounds__(256) void k_agg0(const int2* __restrict__ edgb,
                                              const int* __restrict__ cnt,
                                              const short* __restrict__ xb,
                                              const float* __restrict__ epsp,
                                              short* __restrict__ z) {
    int node = (blockIdx.x * 256 + threadIdx.x) >> 5;
    int lane = threadIdx.x & 31;
    if (node >= NNODES) return;
    const float eps1 = 1.0f + epsp[0];
    const int4* eb4 = reinterpret_cast<const int4*>(edgb + (size_t)node * MAXDEG);
    int p1 = min(cnt[node], MAXDEG);
    uint2 hv = *reinterpret_cast<const uint2*>(xb + (size_t)node * 128 + lane * 4);
    float a0 = eps1 * __builtin_bit_cast(float, hv.x << 16);
    float a1 = eps1 * __builtin_bit_cast(float, hv.x & 0xffff0000u);
    float a2 = eps1 * __builtin_bit_cast(float, hv.y << 16);
    float a3 = eps1 * __builtin_bit_cast(float, hv.y & 0xffff0000u);
    float b0 = 0.f, b1 = 0.f, b2 = 0.f, b3 = 0.f;
    int p = 0;
    for (; p + 3 < p1; p += 4) {
        int4 e01 = eb4[p >> 1], e23 = eb4[(p >> 1) + 1];
        float w0 = __builtin_bit_cast(float, e01.y);
        float w1 = __builtin_bit_cast(float, e01.w);
        float w2 = __builtin_bit_cast(float, e23.y);
        float w3 = __builtin_bit_cast(float, e23.w);
        uint2 v0 = *reinterpret_cast<const uint2*>(xb + (size_t)e01.x * 128 + lane * 4);
        uint2 v1 = *reinterpret_cast<const uint2*>(xb + (size_t)e01.z * 128 + lane * 4);
        uint2 v2 = *reinterpret_cast<const uint2*>(xb + (size_t)e23.x * 128 + lane * 4);
        uint2 v3 = *reinterpret_cast<const uint2*>(xb + (size_t)e23.z * 128 + lane * 4);
        a0 += fmaxf(__builtin_bit_cast(float, v0.x << 16) * w0, 0.f);
        a1 += fmaxf(__builtin_bit_cast(float, v0.x & 0xffff0000u) * w0, 0.f);
        a2 += fmaxf(__builtin_bit_cast(float, v0.y << 16) * w0, 0.f);
        a3 += fmaxf(__builtin_bit_cast(float, v0.y & 0xffff0000u) * w0, 0.f);
        b0 += fmaxf(__builtin_bit_cast(float, v1.x << 16) * w1, 0.f);
        b1 += fmaxf(__builtin_bit_cast(float, v1.x & 0xffff0000u) * w1, 0.f);
        b2 += fmaxf(__builtin_bit_cast(float, v1.y << 16) * w1, 0.f);
        b3 += fmaxf(__builtin_bit_cast(float, v1.y & 0xffff0000u) * w1, 0.f);
        a0 += fmaxf(__builtin_bit_cast(float, v2.x << 16) * w2, 0.f);
        a1 += fmaxf(__builtin_bit_cast(float, v2.x & 0xffff0000u) * w2, 0.f);
        a2 += fmaxf(__builtin_bit_cast(float, v2.y << 16) * w2, 0.f);
        a3 += fmaxf(__builtin_bit_cast(float, v2.y & 0xffff0000u) * w2, 0.f);
        b0 += fmaxf(__builtin_bit_cast(float, v3.x << 16) * w3, 0.f);
        b1 += fmaxf(__builtin_bit_cast(float, v3.x & 0xffff0000u) * w3, 0.f);
        b2 += fmaxf(__builtin_bit_cast(float, v3.y << 16) * w3, 0.f);
        b3 += fmaxf(__builtin_bit_cast(float, v3.y & 0xffff0000u) * w3, 0.f);
    }
    const int2* eb = reinterpret_cast<const int2*>(eb4);
    for (; p < p1; ++p) {
        int2 q0 = eb[p];
        float w0 = __builtin_bit_cast(float, q0.y);
        uint2 v0 = *reinterpret_cast<const uint2*>(xb + (size_t)q0.x * 128 + lane * 4);
        a0 += fmaxf(__builtin_bit_cast(float, v0.x << 16) * w0, 0.f);
        a1 += fmaxf(__builtin_bit_cast(float, v0.x & 0xffff0000u) * w0, 0.f);
        a2 += fmaxf(__builtin_bit_cast(float, v0.y << 16) * w0, 0.f);
        a3 += fmaxf(__builtin_bit_cast(float, v0.y & 0xffff0000u) * w0, 0.f);
    }
    short4 o;
    o.x = f2bf(a0 + b0); o.y = f2bf(a1 + b1); o.z = f2bf(a2 + b2); o.w = f2bf(a3 + b3);
    *reinterpret_cast<short4*>(z + (size_t)node * 128 + lane * 4) = o;
}

// ================================================================ gather layers 1,2 (wave/node, scalar meta)
__global__ __launch_bounds__(256) void k_agg256(const int2* __restrict__ edgb,
                                                const int* __restrict__ cnt,
                                                const short* __restrict__ h,
                                                const float* __restrict__ epsp,
                                                short* __restrict__ z) {
    int node = (blockIdx.x * 256 + threadIdx.x) >> 6;
    int lane = threadIdx.x & 63;
    if (node >= NNODES) return;
    node = __builtin_amdgcn_readfirstlane(node);
    const float eps1 = 1.0f + epsp[0];
    const int2* eb = edgb + (size_t)node * MAXDEG;
    int p1 = min(cnt[node], MAXDEG);
    uint2 hv = *reinterpret_cast<const uint2*>(h + (size_t)node * 256 + lane * 4);
    float a0 = eps1 * __builtin_bit_cast(float, hv.x << 16);
    float a1 = eps1 * __builtin_bit_cast(float, hv.x & 0xffff0000u);
    float a2 = eps1 * __builtin_bit_cast(float, hv.y << 16);
    float a3 = eps1 * __builtin_bit_cast(float, hv.y & 0xffff0000u);
    float b0 = 0.f, b1 = 0.f, b2 = 0.f, b3 = 0.f;
    int p = 0;
    for (; p + 3 < p1; p += 4) {
        int2 q0 = eb[p], q1 = eb[p + 1], q2 = eb[p + 2], q3 = eb[p + 3];
        float w0 = __builtin_bit_cast(float, q0.y);
        float w1 = __builtin_bit_cast(float, q1.y);
        float w2 = __builtin_bit_cast(float, q2.y);
        float w3 = __builtin_bit_cast(float, q3.y);
        uint2 v0 = *reinterpret_cast<const uint2*>(h + (size_t)q0.x * 256 + lane * 4);
        uint2 v1 = *reinterpret_cast<const uint2*>(h + (size_t)q1.x * 256 + lane * 4);
        uint2 v2 = *reinterpret_cast<const uint2*>(h + (size_t)q2.x * 256 + lane * 4);
        uint2 v3 = *reinterpret_cast<const uint2*>(h + (size_t)q3.x * 256 + lane * 4);
        a0 += __builtin_bit_cast(float, v0.x << 16) * w0;
        a1 += __builtin_bit_cast(float, v0.x & 0xffff0000u) * w0;
        a2 += __builtin_bit_cast(float, v0.y << 16) * w0;
        a3 += __builtin_bit_cast(float, v0.y & 0xffff0000u) * w0;
        b0 += __builtin_bit_cast(float, v1.x << 16) * w1;
        b1 += __builtin_bit_cast(float, v1.x & 0xffff0000u) * w1;
        b2 += __builtin_bit_cast(float, v1.y << 16) * w1;
        b3 += __builtin_bit_cast(float, v1.y & 0xffff0000u) * w1;
        a0 += __builtin_bit_cast(float, v2.x << 16) * w2;
        a1 += __builtin_bit_cast(float, v2.x & 0xffff0000u) * w2;
        a2 += __builtin_bit_cast(float, v2.y << 16) * w2;
        a3 += __builtin_bit_cast(float, v2.y & 0xffff0000u) * w2;
        b0 += __builtin_bit_cast(float, v3.x << 16) * w3;
        b1 += __builtin_bit_cast(float, v3.x & 0xffff0000u) * w3;
        b2 += __builtin_bit_cast(float, v3.y << 16) * w3;
        b3 += __builtin_bit_cast(float, v3.y & 0xffff0000u) * w3;
    }
    for (; p < p1; ++p) {
        int2 q0 = eb[p];
        float w0 = __builtin_bit_cast(float, q0.y);
        uint2 v0 = *reinterpret_cast<const uint2*>(h + (size_t)q0.x * 256 + lane * 4);
        a0 += __builtin_bit_cast(float, v0.x << 16) * w0;
        a1 += __builtin_bit_cast(float, v0.x & 0xffff0000u) * w0;
        a2 += __builtin_bit_cast(float, v0.y << 16) * w0;
        a3 += __builtin_bit_cast(float, v0.y & 0xffff0000u) * w0;
    }
    ushort e0 = (ushort)f2bf(a0 + b0), e1 = (ushort)f2bf(a1 + b1);
    ushort e2 = (ushort)f2bf(a2 + b2), e3 = (ushort)f2bf(a3 + b3);
    uint2 ov;
    ov.x = e0 | ((unsigned)e1 << 16);
    ov.y = e2 | ((unsigned)e3 << 16);
    *reinterpret_cast<uint2*>(z + (size_t)node * 256 + lane * 4) = ov;
}

// ================================================================ fused MLP, 64-row blocks (r11 shape)
// 8 waves: all 64 rows (m=4), 32-col slice (n=2). Weight frag feeds 4 MFMAs.
// t in two 256-col LDS groups. s_setprio(1) around MFMA clusters (T5).
template<int DIN, bool RELU_OUT, bool FUSE_ATT>
__global__ __launch_bounds__(512, 4) void k_mlp(
    const short* __restrict__ zin,   // [MPAD][DIN]
    const short* __restrict__ W1F,   // fragment-major, T=32, KC=DIN/32
    const float* __restrict__ b1, const float* __restrict__ bn1,  // [4][512]
    const short* __restrict__ W2F,   // fragment-major, T=16, KC=16
    const float* __restrict__ b2, const float* __restrict__ bn2,  // [4][256]
    short* __restrict__ hout,        // [MPAD][256]
    const float* __restrict__ attW, const float* __restrict__ attb,
    float* __restrict__ nkout)
{
    __shared__ __align__(16) short zs[64 * DIN];     // 32 KB (16 KB layer0)
    __shared__ __align__(16) short tbuf[64 * 256];   // 32 KB

    const int tid = threadIdx.x;
    const int r0 = blockIdx.x * 64;
    const int lane = tid & 63;
    const int wc = tid >> 6;
    constexpr int KC1 = DIN / 32;
    constexpr int CH = DIN / 8;

    #pragma unroll
    for (int i = 0; i < 64 * CH / 512; ++i) {
        int cid = i * 512 + tid;
        int r = cid / CH, cl = cid & (CH - 1);
        gload16(zin + (size_t)(r0 + r) * DIN + ((cl ^ (r & 7)) << 3),
                (char*)zs + cid * 16);
    }
    __syncthreads();

    f32x4 acc2[4][2];
    #pragma unroll
    for (int m = 0; m < 4; ++m)
        #pragma unroll
        for (int n = 0; n < 2; ++n)
            acc2[m][n] = (f32x4){0.f, 0.f, 0.f, 0.f};

    #pragma unroll
    for (int g = 0; g < 2; ++g) {
        f32x4 acc[4][2];
        #pragma unroll
        for (int m = 0; m < 4; ++m)
            #pragma unroll
            for (int n = 0; n < 2; ++n)
                acc[m][n] = (f32x4){0.f, 0.f, 0.f, 0.f};
        #pragma unroll
        for (int kt = 0; kt < DIN; kt += 64) {
            #pragma unroll
            for (int ks = 0; ks < 2; ++ks) {
                bf16x8 af[4], bfr[2];
                #pragma unroll
                for (int m = 0; m < 4; ++m) {
                    int zr = m * 16 + (lane & 15);
                    int zc = (kt >> 3) + ks * 4 + (lane >> 4);
                    af[m] = *(const bf16x8*)((const char*)zs + zr * (DIN * 2)
                                             + ((zc ^ (zr & 7)) << 4));
                }
                #pragma unroll
                for (int n = 0; n < 2; ++n) {
                    int T = g * 16 + wc * 2 + n;
                    int C = (kt >> 5) + ks;
                    bfr[n] = *(const bf16x8*)(W1F + (((size_t)T * KC1 + C) * 64 + lane) * 8);
                }
                __builtin_amdgcn_s_setprio(1);
                #pragma unroll
                for (int m = 0; m < 4; ++m)
                    #pragma unroll
                    for (int n = 0; n < 2; ++n)
                        acc[m][n] = __builtin_amdgcn_mfma_f32_16x16x32_bf16(bfr[n], af[m], acc[m][n], 0, 0, 0);
                __builtin_amdgcn_s_setprio(0);
            }
        }
        {
            const int cb = wc * 32 + 4 * (lane >> 4);
            #pragma unroll
            for (int n = 0; n < 2; ++n) {
                int c = cb + n * 16;
                int gc = g * 256 + c;
                float4 ga = *reinterpret_cast<const float4*>(bn1 + gc);
                float4 be = *reinterpret_cast<const float4*>(bn1 + 512 + gc);
                float4 mu = *reinterpret_cast<const float4*>(bn1 + 1024 + gc);
                float4 va = *reinterpret_cast<const float4*>(bn1 + 1536 + gc);
                float4 bi = *reinterpret_cast<const float4*>(b1 + gc);
                float sx = ga.x * rsqrtf(va.x + 1e-5f);
                float sy = ga.y * rsqrtf(va.y + 1e-5f);
                float sz = ga.z * rsqrtf(va.z + 1e-5f);
                float sw = ga.w * rsqrtf(va.w + 1e-5f);
                float hx = be.x - mu.x * sx + bi.x * sx;
                float hy = be.y - mu.y * sy + bi.y * sy;
                float hz = be.z - mu.z * sz + bi.z * sz;
                float hw_ = be.w - mu.w * sw + bi.w * sw;
                #pragma unroll
                for (int m = 0; m < 4; ++m) {
                    int r = m * 16 + (lane & 15);
                    float o0 = fmaxf(acc[m][n][0] * sx + hx, 0.f);
                    float o1 = fmaxf(acc[m][n][1] * sy + hy, 0.f);
                    float o2 = fmaxf(acc[m][n][2] * sz + hz, 0.f);
                    float o3 = fmaxf(acc[m][n][3] * sw + hw_, 0.f);
                    ushort e0 = (ushort)f2bf(o0), e1 = (ushort)f2bf(o1);
                    ushort e2 = (ushort)f2bf(o2), e3 = (ushort)f2bf(o3);
                    uint2 ov;
                    ov.x = e0 | ((unsigned)e1 << 16);
                    ov.y = e2 | ((unsigned)e3 << 16);
                    *reinterpret_cast<uint2*>((char*)tbuf + r * 512
                                              + (((c >> 3) ^ (r & 7)) << 4) + ((c & 4) << 1)) = ov;
                }
            }
        }
        __syncthreads();

        #pragma unroll
        for (int kt = 0; kt < 256; kt += 64) {
            #pragma unroll
            for (int ks = 0; ks < 2; ++ks) {
                bf16x8 af[4], bfr[2];
                #pragma unroll
                for (int m = 0; m < 4; ++m) {
                    int tr = m * 16 + (lane & 15);
                    int tc = (kt >> 3) + ks * 4 + (lane >> 4);
                    af[m] = *(const bf16x8*)((const char*)tbuf + tr * 512
                                             + ((tc ^ (tr & 7)) << 4));
                }
                #pragma unroll
                for (int n = 0; n < 2; ++n) {
                    int T2 = wc * 2 + n;
                    int C2 = g * 8 + (kt >> 5) + ks;
                    bfr[n] = *(const bf16x8*)(W2F + (((size_t)T2 * 16 + C2) * 64 + lane) * 8);
                }
                __builtin_amdgcn_s_setprio(1);
                #pragma unroll
                for (int m = 0; m < 4; ++m)
                    #pragma unroll
                    for (int n = 0; n < 2; ++n)
                        acc2[m][n] = __builtin_amdgcn_mfma_f32_16x16x32_bf16(bfr[n], af[m], acc2[m][n], 0, 0, 0);
                __builtin_amdgcn_s_setprio(0);
            }
        }
        if (g == 0) __syncthreads();
    }

    {
        const int cb = wc * 32 + 4 * (lane >> 4);
        float4 scl[2], shf[2];
        #pragma unroll
        for (int n = 0; n < 2; ++n) {
            int c = cb + n * 16;
            float4 ga = *reinterpret_cast<const float4*>(bn2 + c);
            float4 be = *reinterpret_cast<const float4*>(bn2 + 256 + c);
            float4 mu = *reinterpret_cast<const float4*>(bn2 + 512 + c);
            float4 va = *reinterpret_cast<const float4*>(bn2 + 768 + c);
            float4 bi = *reinterpret_cast<const float4*>(b2 + c);
            scl[n].x = ga.x * rsqrtf(va.x + 1e-5f);
            scl[n].y = ga.y * rsqrtf(va.y + 1e-5f);
            scl[n].z = ga.z * rsqrtf(va.z + 1e-5f);
            scl[n].w = ga.w * rsqrtf(va.w + 1e-5f);
            shf[n].x = be.x - mu.x * scl[n].x + bi.x * scl[n].x;
            shf[n].y = be.y - mu.y * scl[n].y + bi.y * scl[n].y;
            shf[n].z = be.z - mu.z * scl[n].z + bi.z * scl[n].z;
            shf[n].w = be.w - mu.w * scl[n].w + bi.w * scl[n].w;
        }
        if constexpr (!FUSE_ATT) {
            #pragma unroll
            for (int n = 0; n < 2; ++n) {
                int c = cb + n * 16;
                #pragma unroll
                for (int m = 0; m < 4; ++m) {
                    int r = r0 + m * 16 + (lane & 15);
                    float o0 = acc2[m][n][0] * scl[n].x + shf[n].x;
                    float o1 = acc2[m][n][1] * scl[n].y + shf[n].y;
                    float o2 = acc2[m][n][2] * scl[n].z + shf[n].z;
                    float o3 = acc2[m][n][3] * scl[n].w + shf[n].w;
                    if (RELU_OUT) {
                        o0 = fmaxf(o0, 0.f); o1 = fmaxf(o1, 0.f);
                        o2 = fmaxf(o2, 0.f); o3 = fmaxf(o3, 0.f);
                    }
                    short4 ov;
                    ov.x = f2bf(o0); ov.y = f2bf(o1); ov.z = f2bf(o2); ov.w = f2bf(o3);
                    *reinterpret_cast<short4*>(hout + (size_t)r * 256 + c) = ov;
                }
            }
        } else {
            float* attp = (float*)zs;
            #pragma unroll
            for (int m = 0; m < 4; ++m) {
                float s = 0.f;
                #pragma unroll
                for (int n = 0; n < 2; ++n) {
                    int c = cb + n * 16;
                    float4 aw = *reinterpret_cast<const float4*>(attW + c);
                    float o0 = acc2[m][n][0] * scl[n].x + shf[n].x;
                    float o1 = acc2[m][n][1] * scl[n].y + shf[n].y;
                    float o2 = acc2[m][n][2] * scl[n].z + shf[n].z;
                    float o3 = acc2[m][n][3] * scl[n].w + shf[n].w;
                    s += bf2f((ushort)f2bf(o0)) * aw.x + bf2f((ushort)f2bf(o1)) * aw.y
                       + bf2f((ushort)f2bf(o2)) * aw.z + bf2f((ushort)f2bf(o3)) * aw.w;
                }
                s += __shfl_xor(s, 16);
                s += __shfl_xor(s, 32);
                if (lane < 16) attp[wc * 64 + m * 16 + lane] = s;
            }
            __syncthreads();
            if (tid < 64) {
                float d = 0.f;
                #pragma unroll
                for (int w2 = 0; w2 < 8; ++w2) d += attp[w2 * 64 + tid];
                int r = r0 + tid;
                if (r < NNODES)
                    nkout[r] = 1.f / (1.f + expf(-(d + attb[0])));
            }
        }
    }
}

// ================================================================ edge keys
__global__ __launch_bounds__(256) void k_edge(const int* __restrict__ ei,
                                              const float* __restrict__ nk,
                                              float* __restrict__ ek) {
    int e = blockIdx.x * 256 + threadIdx.x;
    if (e >= NEDGES) return;
    ek[e] = nk[ei[e]] * nk[ei[NEDGES + e]];
}

// ================================================================
extern "C" void kernel_launch(void* const* d_in, const int* in_sizes, int n_in,
                              void* d_out, int out_size, void* d_ws, size_t ws_size,
                              hipStream_t stream) {
    const float* x        = (const float*)d_in[0];
    const int*   ei       = (const int*)d_in[1];
    const float* node_imp = (const float*)d_in[2];
    const float* edge_imp = (const float*)d_in[3];
    const float* c0_W1    = (const float*)d_in[4];
    const float* c0_b1    = (const float*)d_in[5];
    const float* c0_bn    = (const float*)d_in[6];
    const float* c0_W2    = (const float*)d_in[7];
    const float* c0_b2    = (const float*)d_in[8];
    const float* c0_eps   = (const float*)d_in[9];
    const float* cs_W1    = (const float*)d_in[10];
    const float* cs_b1    = (const float*)d_in[11];
    const float* cs_bn    = (const float*)d_in[12];
    const float* cs_W2    = (const float*)d_in[13];
    const float* cs_b2    = (const float*)d_in[14];
    const float* cs_eps   = (const float*)d_in[15];
    const float* obn      = (const float*)d_in[16];
    const float* att_W    = (const float*)d_in[17];
    const float* att_b    = (const float*)d_in[18];
    float* out = (float*)d_out;

    const int* e_src = ei;
    const int* e_dst = ei + NEDGES;

    // workspace layout
    short* hA  = (short*)d_ws;                  // [MPAD][256]
    short* hBv = hA + (size_t)MPAD * 256;       // [MPAD][256]
    short* zb  = hBv + (size_t)MPAD * 256;      // [MPAD][256]
    short* wT  = zb + (size_t)MPAD * 256;       // 720896 bf16 (fragment-major)
    short* xb  = wT + 720896;                   // [MPAD][128]
    int2*  edgb = (int2*)(xb + (size_t)MPAD * 128);        // [NNODES][MAXDEG]
    int*   cnt  = (int*)(edgb + (size_t)NNODES * MAXDEG);  // N

    const short* WT_c0W1  = wT + 0;
    const short* WT_cs1_0 = wT + 65536;
    const short* WT_cs1_1 = wT + 196608;
    const short* WT_c0W2  = wT + 327680;
    const short* WT_cs2_0 = wT + 458752;
    const short* WT_cs2_1 = wT + 589824;

    dim3 blk(256);
    const int eb = (NEDGES + 255) / 256;
    const int mgrid = MPAD / 64;   // 314
    const int agrid0 = (NNODES * 32 + 255) / 256;
    const int agrid1 = (NNODES * 64 + 255) / 256;

    // ---- prep (weights + xb + cnt zero) + bucket fill
    const int prepN = 720896 + NNODES * 16 + NNODES;
    k_prep<<<(prepN + 255) / 256, blk, 0, stream>>>(c0_W1, cs_W1, c0_W2, cs_W2,
                                                    x, node_imp, wT, xb, cnt);
    k_fill<<<eb, blk, 0, stream>>>(e_dst, e_src, edge_imp, cnt, edgb);

    // ---- layer 0
    k_agg0<<<agrid0, blk, 0, stream>>>(edgb, cnt, xb, c0_eps, zb);
    k_mlp<128, true, false><<<mgrid, 512, 0, stream>>>(zb, WT_c0W1, c0_b1, c0_bn,
        WT_c0W2, c0_b2, obn, hA, nullptr, nullptr, nullptr);
    // ---- layer 1
    k_agg256<<<agrid1, blk, 0, stream>>>(edgb, cnt, hA, cs_eps, zb);
    k_mlp<256, true, false><<<mgrid, 512, 0, stream>>>(zb, WT_cs1_0, cs_b1, cs_bn,
        WT_cs2_0, cs_b2, obn + 1024, hBv, nullptr, nullptr, nullptr);
    // ---- layer 2 (+ fused attention -> nk in d_out)
    k_agg256<<<agrid1, blk, 0, stream>>>(edgb, cnt, hBv, cs_eps + 1, zb);
    k_mlp<256, false, true><<<mgrid, 512, 0, stream>>>(zb, WT_cs1_1, cs_b1 + 512, cs_bn + 2048,
        WT_cs2_1, cs_b2 + 256, obn + 2048, nullptr, att_W, att_b, out);

    // ---- edge keys
    k_edge<<<eb, blk, 0, stream>>>(ei, out, out + NNODES);
}